// Round 1
// baseline (213.483 us; speedup 1.0000x reference)
//
#include <hip/hip_runtime.h>
#include <cmath>

// Problem constants: (N,C,H,W) = (16,3,512,512), fp32
#define PLANE (512*512)          // 262144
#define NPLANES 48               // N*C
#define NEL (48*PLANE)           // 12582912

struct Taps { float k[9]; };

// ---------------------------------------------------------------------------
// Kernel 1: fused log(x+1e-6) + W-blur + H-blur, 64x64 output tiles, halo 4.
// grid (8, 8, 96): x=tile_w, y=tile_h, z=plane (0..47 image E, 48..95 image G)
// ---------------------------------------------------------------------------
__global__ __launch_bounds__(256)
void k_blur_hw(const float* __restrict__ inE, const float* __restrict__ inG,
               float* __restrict__ outE, float* __restrict__ outG, Taps tp)
{
    __shared__ float raw[72*72];   // log values, rows h0-4..h0+67, cols w0-4..w0+67
    __shared__ float wb[72*64];    // W-blurred, 72 rows x 64 output cols

    const int tid = threadIdx.x;
    const int w0 = blockIdx.x * 64;
    const int h0 = blockIdx.y * 64;
    const int z  = blockIdx.z;

    const float* src;
    float* dst;
    if (z < NPLANES) { src = inE + z * PLANE;              dst = outE + z * PLANE; }
    else             { src = inG + (z - NPLANES) * PLANE;  dst = outG + (z - NPLANES) * PLANE; }

    // Phase 1: load 72x72 with symmetric fold at 0/511, apply log once/elem
    for (int j = tid; j < 72*72; j += 256) {
        int r = j / 72;
        int c = j - r * 72;
        int h = h0 + r - 4; h = (h < 0) ? (-1 - h) : ((h > 511) ? (1023 - h) : h);
        int w = w0 + c - 4; w = (w < 0) ? (-1 - w) : ((w > 511) ? (1023 - w) : w);
        raw[j] = logf(src[h * 512 + w] + 1e-6f);
    }
    __syncthreads();

    // Phase 2: blur along W -> wb[72][64]
    for (int j = tid; j < 72*64; j += 256) {
        int r = j >> 6, c = j & 63;
        const float* rr = &raw[r * 72 + c];
        float s = 0.f;
#pragma unroll
        for (int t = 0; t < 9; ++t) s += tp.k[t] * rr[t];
        wb[j] = s;
    }
    __syncthreads();

    // Phase 3: blur along H, write 64x64 tile
    for (int j = tid; j < 64*64; j += 256) {
        int r = j >> 6, c = j & 63;
        float s = 0.f;
#pragma unroll
        for (int t = 0; t < 9; ++t) s += tp.k[t] * wb[(r + t) * 64 + c];
        dst[(h0 + r) * 512 + (w0 + c)] = s;
    }
}

// ---------------------------------------------------------------------------
// Kernel 2: C-blur + N-blur + loss terms, fused. One thread per (h,w); each
// thread owns all 48 (n,c) values. C axis (size 3, radius 4): symmetric fold
// is period-6 mirror -> precomputed index tables. N axis (size 16): simple
// edge mirror. Loss accumulated per block -> part[blockIdx].
// grid (1024), block (256): 1024*256 = 262144 = PLANE
// ---------------------------------------------------------------------------
__global__ __launch_bounds__(256)
void k_cn_loss(const float* __restrict__ Ae, const float* __restrict__ Ag,
               const float* __restrict__ Ie, const float* __restrict__ Ig,
               float* __restrict__ part, Taps tp)
{
    const int hw = blockIdx.x * 256 + threadIdx.x;

    // symmetric fold of c-4+t for size-3 axis (period-6 mirror), c = 0,1,2
    const int F3[3][9] = {
        {2,2,1,0,0,1,2,2,1},
        {2,1,0,0,1,2,2,1,0},
        {1,0,0,1,2,2,1,0,0}
    };

    float tce[48];  // C-blurred log(E)
    float tcg[48];  // C-blurred log(G)

    {
        float v[48];
#pragma unroll
        for (int j = 0; j < 48; ++j) v[j] = Ae[j * PLANE + hw];
#pragma unroll
        for (int n = 0; n < 16; ++n)
#pragma unroll
            for (int c = 0; c < 3; ++c) {
                float s = 0.f;
#pragma unroll
                for (int t = 0; t < 9; ++t) s += tp.k[t] * v[n * 3 + F3[c][t]];
                tce[n * 3 + c] = s;
            }
    }
    {
        float v[48];
#pragma unroll
        for (int j = 0; j < 48; ++j) v[j] = Ag[j * PLANE + hw];
#pragma unroll
        for (int n = 0; n < 16; ++n)
#pragma unroll
            for (int c = 0; c < 3; ++c) {
                float s = 0.f;
#pragma unroll
                for (int t = 0; t < 9; ++t) s += tp.k[t] * v[n * 3 + F3[c][t]];
                tcg[n * 3 + c] = s;
            }
    }

    // N-blur computed inline (keeps register pressure ~2x48), then loss terms
    float acc = 0.f;
#pragma unroll
    for (int n = 0; n < 16; ++n) {
#pragma unroll
        for (int c = 0; c < 3; ++c) {
            float se = 0.f, sg = 0.f;
#pragma unroll
            for (int t = 0; t < 9; ++t) {
                int m = n - 4 + t;
                m = (m < 0) ? (-1 - m) : ((m > 15) ? (31 - m) : m);
                se += tp.k[t] * tce[m * 3 + c];
                sg += tp.k[t] * tcg[m * 3 + c];
            }
            const int j = n * 3 + c;
            float ie = Ie[j * PLANE + hw];
            float ig = Ig[j * PLANE + hw];
            float le = logf(ie + 1e-6f);
            float lg = logf(ig + 1e-6f);
            float Re = expf(le - se);
            float Rg = expf(lg - sg);
            float Le = expf(se);
            float Lg = expf(sg);
            float dr = Re - Rg;
            float dl = Le - Lg;
            acc += dr * dr + dl * dl;
        }
    }

    __shared__ float red[256];
    red[threadIdx.x] = acc;
    __syncthreads();
#pragma unroll
    for (int s = 128; s > 0; s >>= 1) {
        if (threadIdx.x < s) red[threadIdx.x] += red[threadIdx.x + s];
        __syncthreads();
    }
    if (threadIdx.x == 0) part[blockIdx.x] = red[0];
}

// ---------------------------------------------------------------------------
// Kernel 3: reduce 1024 partials, scale by 1/NEL
// ---------------------------------------------------------------------------
__global__ __launch_bounds__(256)
void k_final(const float* __restrict__ part, float* __restrict__ out)
{
    __shared__ float red[256];
    float a = 0.f;
    for (int i = threadIdx.x; i < 1024; i += 256) a += part[i];
    red[threadIdx.x] = a;
    __syncthreads();
#pragma unroll
    for (int s = 128; s > 0; s >>= 1) {
        if (threadIdx.x < s) red[threadIdx.x] += red[threadIdx.x + s];
        __syncthreads();
    }
    if (threadIdx.x == 0) out[0] = red[0] * (1.0f / (float)NEL);
}

extern "C" void kernel_launch(void* const* d_in, const int* in_sizes, int n_in,
                              void* d_out, int out_size, void* d_ws, size_t ws_size,
                              hipStream_t stream) {
    const float* Ie = (const float*)d_in[0];
    const float* Ig = (const float*)d_in[1];

    // Gaussian taps: sigma=1, radius=int(4*1+0.5)=4, computed in double then
    // cast to float -- matches the reference's float64 normalize + float32 cast.
    Taps tp;
    {
        double kk[9], s = 0.0;
        for (int i = 0; i < 9; ++i) { double x = (double)(i - 4); kk[i] = exp(-0.5 * x * x); s += kk[i]; }
        for (int i = 0; i < 9; ++i) tp.k[i] = (float)(kk[i] / s);
    }

    float* Ae   = (float*)d_ws;          // HW-blurred log(Ie), 48 MB
    float* Ag   = Ae + NEL;              // HW-blurred log(Ig), 48 MB
    float* part = Ag + NEL;              // 1024 block partials

    dim3 g1(8, 8, 96);
    k_blur_hw<<<g1, 256, 0, stream>>>(Ie, Ig, Ae, Ag, tp);
    k_cn_loss<<<1024, 256, 0, stream>>>(Ae, Ag, Ie, Ig, part, tp);
    k_final<<<1, 256, 0, stream>>>(part, (float*)d_out);
}